// Round 1
// baseline (421.744 us; speedup 1.0000x reference)
//
#include <hip/hip_runtime.h>
#include <stdint.h>

// MultiHeadAttention: B=4, S=2048, D_MODEL=1024, H=16, dh=64
// Pipeline:
//   1. transpose_w : w{q,k,v,o} fp32 (K x N) -> bf16 W^T (N x K) in ws
//   2. gemm_qkv    : X @ W + b -> Q (scaled 0.125, B,H,S,dh), K (B,H,S,dh), V^T (B,H,dh,S), bf16
//   3. attn        : flash attention per (b,h), online softmax, ctx bf16 (B,S,H*dh)
//   4. gemm_out    : ctx @ wo^T + bo -> d_out fp32 (B,S,1024)
// Workspace: 4*2MB (wT) + 3*16MB (Q,K,Vt) + 16MB (ctx) = 72MB, fully rewritten each call.

typedef unsigned short u16;
typedef __attribute__((ext_vector_type(8))) short bf16x8;
typedef __attribute__((ext_vector_type(4))) float f32x4;

#define LOG2E 1.4426950408889634f

__device__ __forceinline__ u16 f2bf(float f) {
  uint32_t u = __builtin_bit_cast(uint32_t, f);
  u += 0x7fffu + ((u >> 16) & 1u);   // RNE
  return (u16)(u >> 16);
}

// ---------------- weight transpose + bf16 convert ----------------
__global__ __launch_bounds__(256) void transpose_w(
    const float* __restrict__ W0, const float* __restrict__ W1,
    const float* __restrict__ W2, const float* __restrict__ W3,
    u16* __restrict__ Wt)
{
  const int z = blockIdx.z;
  const float* W = (z == 0) ? W0 : (z == 1) ? W1 : (z == 2) ? W2 : W3;
  u16* T = Wt + ((size_t)z << 20);
  const int n0 = blockIdx.x * 64, k0 = blockIdx.y * 64;
  const int tid = threadIdx.x;
  const int r = tid >> 4, c4 = (tid & 15) * 4;
  __shared__ float t[64][65];
#pragma unroll
  for (int j = 0; j < 4; ++j) {
    const int row = r + j * 16;
    const float4 v = *(const float4*)(W + (size_t)(k0 + row) * 1024 + n0 + c4);
    t[c4 + 0][row] = v.x; t[c4 + 1][row] = v.y;
    t[c4 + 2][row] = v.z; t[c4 + 3][row] = v.w;
  }
  __syncthreads();
#pragma unroll
  for (int j = 0; j < 4; ++j) {
    const int nrow = r + j * 16;
    ushort4 o;
    o.x = f2bf(t[nrow][c4 + 0]); o.y = f2bf(t[nrow][c4 + 1]);
    o.z = f2bf(t[nrow][c4 + 2]); o.w = f2bf(t[nrow][c4 + 3]);
    *(ushort4*)(T + (size_t)(n0 + nrow) * 1024 + k0 + c4) = o;
  }
}

// ---------------- QKV projection GEMM ----------------
// X fp32 (8192 x 1024) @ W (1024 x 1024, via bf16 W^T) + bias -> bf16.
// 128x128 tile, 4 waves (each 64x64 = 4x4 fragments of 16x16x32), BK=32.
// LDS row stride 56 elems (112B = 7*16B): 16B-aligned b128 reads, 8 bank groups.
__global__ __launch_bounds__(256) void gemm_qkv(
    const float* __restrict__ Xq, const float* __restrict__ Xk, const float* __restrict__ Xv,
    const u16* __restrict__ Wtq, const u16* __restrict__ Wtk, const u16* __restrict__ Wtv,
    const float* __restrict__ Bq, const float* __restrict__ Bk, const float* __restrict__ Bv,
    u16* __restrict__ Qo, u16* __restrict__ Ko, u16* __restrict__ Vto)
{
  const int z = blockIdx.z;
  const float* X = (z == 0) ? Xq : (z == 1) ? Xk : Xv;
  const u16* Wt  = (z == 0) ? Wtq : (z == 1) ? Wtk : Wtv;
  const float* Bi = (z == 0) ? Bq : (z == 1) ? Bk : Bv;

  const int m0 = blockIdx.y * 128;
  const int n0 = blockIdx.x * 128;
  const int tid = threadIdx.x;
  const int w = tid >> 6, l = tid & 63, lo = l & 15, hi = l >> 4;
  const int wr = w >> 1, wc = w & 1;

  __shared__ __align__(16) u16 As[128 * 56];
  __shared__ __align__(16) u16 Bs[128 * 56];

  const f32x4 fz = {0.f, 0.f, 0.f, 0.f};
  f32x4 acc[4][4];
#pragma unroll
  for (int m = 0; m < 4; ++m)
#pragma unroll
    for (int n = 0; n < 4; ++n) acc[m][n] = fz;

  const int srow = tid >> 1, shalf = (tid & 1) * 16;

  for (int k0 = 0; k0 < 1024; k0 += 32) {
    const float* ap = X + (size_t)(m0 + srow) * 1024 + k0 + shalf;
    const float4 a0 = *(const float4*)(ap);
    const float4 a1 = *(const float4*)(ap + 4);
    const float4 a2 = *(const float4*)(ap + 8);
    const float4 a3 = *(const float4*)(ap + 12);
    const u16* bp = Wt + (size_t)(n0 + srow) * 1024 + k0 + shalf;
    const uint4 b0 = *(const uint4*)(bp);
    const uint4 b1 = *(const uint4*)(bp + 8);

    __syncthreads();   // previous iter's frag reads done before overwrite

    uint4 c0, c1;
    c0.x = (uint32_t)f2bf(a0.x) | ((uint32_t)f2bf(a0.y) << 16);
    c0.y = (uint32_t)f2bf(a0.z) | ((uint32_t)f2bf(a0.w) << 16);
    c0.z = (uint32_t)f2bf(a1.x) | ((uint32_t)f2bf(a1.y) << 16);
    c0.w = (uint32_t)f2bf(a1.z) | ((uint32_t)f2bf(a1.w) << 16);
    c1.x = (uint32_t)f2bf(a2.x) | ((uint32_t)f2bf(a2.y) << 16);
    c1.y = (uint32_t)f2bf(a2.z) | ((uint32_t)f2bf(a2.w) << 16);
    c1.z = (uint32_t)f2bf(a3.x) | ((uint32_t)f2bf(a3.y) << 16);
    c1.w = (uint32_t)f2bf(a3.z) | ((uint32_t)f2bf(a3.w) << 16);
    *(uint4*)&As[srow * 56 + shalf] = c0;
    *(uint4*)&As[srow * 56 + shalf + 8] = c1;
    *(uint4*)&Bs[srow * 56 + shalf] = b0;
    *(uint4*)&Bs[srow * 56 + shalf + 8] = b1;
    __syncthreads();

    bf16x8 af[4], bv_[4];
#pragma unroll
    for (int m = 0; m < 4; ++m)
      af[m] = *(const bf16x8*)&As[(wr * 64 + m * 16 + lo) * 56 + hi * 8];
#pragma unroll
    for (int n = 0; n < 4; ++n)
      bv_[n] = *(const bf16x8*)&Bs[(wc * 64 + n * 16 + lo) * 56 + hi * 8];
#pragma unroll
    for (int m = 0; m < 4; ++m)
#pragma unroll
      for (int n = 0; n < 4; ++n)
        acc[m][n] = __builtin_amdgcn_mfma_f32_16x16x32_bf16(af[m], bv_[n], acc[m][n], 0, 0, 0);
  }

  // epilogue: bias, (Q scale), scatter to attention layouts
#pragma unroll
  for (int m = 0; m < 4; ++m) {
#pragma unroll
    for (int n = 0; n < 4; ++n) {
      const int col = n0 + wc * 64 + n * 16 + lo;   // n = h*64 + d
      const float bc = Bi[col];
      const int h = col >> 6, d = col & 63;
#pragma unroll
      for (int i = 0; i < 4; ++i) {
        const int r = m0 + wr * 64 + m * 16 + hi * 4 + i;  // r = b*2048 + s
        const int b = r >> 11, s = r & 2047;
        float v = acc[m][n][i] + bc;
        if (z == 0) {
          v *= 0.125f;  // fold 1/sqrt(dh)
          Qo[((size_t)((b * 16 + h) * 2048 + s)) * 64 + d] = f2bf(v);
        } else if (z == 1) {
          Ko[((size_t)((b * 16 + h) * 2048 + s)) * 64 + d] = f2bf(v);
        } else {
          Vto[((size_t)((b * 16 + h) * 64 + d)) * 2048 + s] = f2bf(v);
        }
      }
    }
  }
}

// ---------------- flash attention ----------------
// grid (32 q-tiles, 64 b*h), 256 threads = 4 waves, each wave owns 16 q rows.
// KBLK=64. K tile [64][64] and V^T tile [64 d][64 kv] staged in padded LDS (stride 72).
__global__ __launch_bounds__(256) void attn(
    const u16* __restrict__ Q, const u16* __restrict__ K,
    const u16* __restrict__ Vt, const float* __restrict__ mask,
    u16* __restrict__ Ctx)
{
  const int qt = blockIdx.x;
  const int bh = blockIdx.y;
  const int b = bh >> 4, h = bh & 15;
  const int tid = threadIdx.x;
  const int w = tid >> 6, l = tid & 63, lo = l & 15, hi = l >> 4;

  __shared__ __align__(16) u16 Kl[64 * 72];
  __shared__ __align__(16) u16 Vl[64 * 72];
  __shared__ __align__(16) u16 Pl[4][16 * 72];

  const u16* Qb = Q + (size_t)bh * (2048 * 64);
  const u16* Kb = K + (size_t)bh * (2048 * 64);
  const u16* Vb = Vt + (size_t)bh * (64 * 2048);
  const float* mb = mask + (size_t)b * 2048;

  // Q fragments hoisted to registers (rows w*16+lo, k = kk*32 + hi*8 + j)
  const int qrow = qt * 64 + w * 16 + lo;
  const bf16x8 qa0 = *(const bf16x8*)(Qb + (size_t)qrow * 64 + hi * 8);
  const bf16x8 qa1 = *(const bf16x8*)(Qb + (size_t)qrow * 64 + 32 + hi * 8);

  const f32x4 fz = {0.f, 0.f, 0.f, 0.f};
  f32x4 o[4] = {fz, fz, fz, fz};
  float mrun[4] = {-1e30f, -1e30f, -1e30f, -1e30f};
  float lrun[4] = {0.f, 0.f, 0.f, 0.f};

  const int srow = tid >> 2;
  const int sq = (tid & 3) * 16;

  for (int kt = 0; kt < 32; ++kt) {
    const int kv0 = kt * 64;
    // issue global loads before the barrier (overlap with prev-iter compute)
    const u16* kp = Kb + (size_t)(kv0 + srow) * 64 + sq;
    const uint4 k0v = *(const uint4*)kp;
    const uint4 k1v = *(const uint4*)(kp + 8);
    const u16* vp = Vb + (size_t)srow * 2048 + kv0 + sq;
    const uint4 v0v = *(const uint4*)vp;
    const uint4 v1v = *(const uint4*)(vp + 8);
    float mv[4];
#pragma unroll
    for (int nf = 0; nf < 4; ++nf)
      mv[nf] = mb[kv0 + nf * 16 + lo] * (-1.0e9f * LOG2E);

    __syncthreads();
    *(uint4*)&Kl[srow * 72 + sq] = k0v;
    *(uint4*)&Kl[srow * 72 + sq + 8] = k1v;
    *(uint4*)&Vl[srow * 72 + sq] = v0v;
    *(uint4*)&Vl[srow * 72 + sq + 8] = v1v;
    __syncthreads();

    // QK^T: S[q=(hi*4+i)][kv=nf*16+lo], log2 domain
    float s2[4][4];
#pragma unroll
    for (int nf = 0; nf < 4; ++nf) {
      const int krow = (nf * 16 + lo) * 72;
      const bf16x8 kb0 = *(const bf16x8*)&Kl[krow + hi * 8];
      const bf16x8 kb1 = *(const bf16x8*)&Kl[krow + 32 + hi * 8];
      f32x4 a = fz;
      a = __builtin_amdgcn_mfma_f32_16x16x32_bf16(qa0, kb0, a, 0, 0, 0);
      a = __builtin_amdgcn_mfma_f32_16x16x32_bf16(qa1, kb1, a, 0, 0, 0);
#pragma unroll
      for (int i = 0; i < 4; ++i) s2[nf][i] = a[i] * LOG2E + mv[nf];
    }

    // online softmax: row reduce over nf (regs) then 16-lane butterfly
    float sc[4], rs[4];
#pragma unroll
    for (int i = 0; i < 4; ++i) {
      float t0 = fmaxf(fmaxf(s2[0][i], s2[1][i]), fmaxf(s2[2][i], s2[3][i]));
      t0 = fmaxf(t0, __shfl_xor(t0, 1));
      t0 = fmaxf(t0, __shfl_xor(t0, 2));
      t0 = fmaxf(t0, __shfl_xor(t0, 4));
      t0 = fmaxf(t0, __shfl_xor(t0, 8));
      const float mn = fmaxf(mrun[i], t0);
      sc[i] = exp2f(mrun[i] - mn);
      mrun[i] = mn;
      rs[i] = 0.f;
    }
#pragma unroll
    for (int nf = 0; nf < 4; ++nf) {
      const float p0 = exp2f(s2[nf][0] - mrun[0]);
      const float p1 = exp2f(s2[nf][1] - mrun[1]);
      const float p2 = exp2f(s2[nf][2] - mrun[2]);
      const float p3 = exp2f(s2[nf][3] - mrun[3]);
      rs[0] += p0; rs[1] += p1; rs[2] += p2; rs[3] += p3;
      Pl[w][(hi * 4 + 0) * 72 + nf * 16 + lo] = f2bf(p0);
      Pl[w][(hi * 4 + 1) * 72 + nf * 16 + lo] = f2bf(p1);
      Pl[w][(hi * 4 + 2) * 72 + nf * 16 + lo] = f2bf(p2);
      Pl[w][(hi * 4 + 3) * 72 + nf * 16 + lo] = f2bf(p3);
    }
#pragma unroll
    for (int i = 0; i < 4; ++i) {
      rs[i] += __shfl_xor(rs[i], 1);
      rs[i] += __shfl_xor(rs[i], 2);
      rs[i] += __shfl_xor(rs[i], 4);
      rs[i] += __shfl_xor(rs[i], 8);
      lrun[i] = lrun[i] * sc[i] + rs[i];
    }
#pragma unroll
    for (int nf = 0; nf < 4; ++nf) {
      o[nf][0] *= sc[0]; o[nf][1] *= sc[1];
      o[nf][2] *= sc[2]; o[nf][3] *= sc[3];
    }

    __builtin_amdgcn_wave_barrier();  // keep P writes before P reads

    // PV: O[q][d] += P(16x64) @ V(64x64); both operands contiguous LDS rows
    const bf16x8 pa0 = *(const bf16x8*)&Pl[w][lo * 72 + hi * 8];
    const bf16x8 pa1 = *(const bf16x8*)&Pl[w][lo * 72 + 32 + hi * 8];
#pragma unroll
    for (int nf = 0; nf < 4; ++nf) {
      const int vrow = (nf * 16 + lo) * 72;
      const bf16x8 vb0 = *(const bf16x8*)&Vl[vrow + hi * 8];
      const bf16x8 vb1 = *(const bf16x8*)&Vl[vrow + 32 + hi * 8];
      o[nf] = __builtin_amdgcn_mfma_f32_16x16x32_bf16(pa0, vb0, o[nf], 0, 0, 0);
      o[nf] = __builtin_amdgcn_mfma_f32_16x16x32_bf16(pa1, vb1, o[nf], 0, 0, 0);
    }
  }

  float inv[4];
#pragma unroll
  for (int i = 0; i < 4; ++i) inv[i] = 1.f / lrun[i];
#pragma unroll
  for (int nf = 0; nf < 4; ++nf) {
#pragma unroll
    for (int i = 0; i < 4; ++i) {
      const int s = qt * 64 + w * 16 + hi * 4 + i;
      const int d = nf * 16 + lo;
      Ctx[((size_t)((b * 2048 + s) * 16 + h)) * 64 + d] = f2bf(o[nf][i] * inv[i]);
    }
  }
}

// ---------------- output projection GEMM ----------------
__global__ __launch_bounds__(256) void gemm_out(
    const u16* __restrict__ Ctx, const u16* __restrict__ Wt,
    const float* __restrict__ Bo, float* __restrict__ Out)
{
  const int m0 = blockIdx.y * 128;
  const int n0 = blockIdx.x * 128;
  const int tid = threadIdx.x;
  const int w = tid >> 6, l = tid & 63, lo = l & 15, hi = l >> 4;
  const int wr = w >> 1, wc = w & 1;

  __shared__ __align__(16) u16 As[128 * 56];
  __shared__ __align__(16) u16 Bs[128 * 56];

  const f32x4 fz = {0.f, 0.f, 0.f, 0.f};
  f32x4 acc[4][4];
#pragma unroll
  for (int m = 0; m < 4; ++m)
#pragma unroll
    for (int n = 0; n < 4; ++n) acc[m][n] = fz;

  const int srow = tid >> 1, shalf = (tid & 1) * 16;

  for (int k0 = 0; k0 < 1024; k0 += 32) {
    const u16* ap = Ctx + (size_t)(m0 + srow) * 1024 + k0 + shalf;
    const uint4 a0 = *(const uint4*)(ap);
    const uint4 a1 = *(const uint4*)(ap + 8);
    const u16* bp = Wt + (size_t)(n0 + srow) * 1024 + k0 + shalf;
    const uint4 b0 = *(const uint4*)(bp);
    const uint4 b1 = *(const uint4*)(bp + 8);

    __syncthreads();
    *(uint4*)&As[srow * 56 + shalf] = a0;
    *(uint4*)&As[srow * 56 + shalf + 8] = a1;
    *(uint4*)&Bs[srow * 56 + shalf] = b0;
    *(uint4*)&Bs[srow * 56 + shalf + 8] = b1;
    __syncthreads();

    bf16x8 af[4], bv_[4];
#pragma unroll
    for (int m = 0; m < 4; ++m)
      af[m] = *(const bf16x8*)&As[(wr * 64 + m * 16 + lo) * 56 + hi * 8];
#pragma unroll
    for (int n = 0; n < 4; ++n)
      bv_[n] = *(const bf16x8*)&Bs[(wc * 64 + n * 16 + lo) * 56 + hi * 8];
#pragma unroll
    for (int m = 0; m < 4; ++m)
#pragma unroll
      for (int n = 0; n < 4; ++n)
        acc[m][n] = __builtin_amdgcn_mfma_f32_16x16x32_bf16(af[m], bv_[n], acc[m][n], 0, 0, 0);
  }

#pragma unroll
  for (int m = 0; m < 4; ++m) {
#pragma unroll
    for (int n = 0; n < 4; ++n) {
      const int col = n0 + wc * 64 + n * 16 + lo;
      const float bc = Bo[col];
#pragma unroll
      for (int i = 0; i < 4; ++i) {
        const int r = m0 + wr * 64 + m * 16 + hi * 4 + i;
        Out[(size_t)r * 1024 + col] = acc[m][n][i] + bc;
      }
    }
  }
}

extern "C" void kernel_launch(void* const* d_in, const int* in_sizes, int n_in,
                              void* d_out, int out_size, void* d_ws, size_t ws_size,
                              hipStream_t stream) {
  const float* q_in = (const float*)d_in[0];
  const float* k_in = (const float*)d_in[1];
  const float* v_in = (const float*)d_in[2];
  const float* mask = (const float*)d_in[3];
  const float* wq = (const float*)d_in[4];
  const float* bq = (const float*)d_in[5];
  const float* wk = (const float*)d_in[6];
  const float* bk = (const float*)d_in[7];
  const float* wv = (const float*)d_in[8];
  const float* bv = (const float*)d_in[9];
  const float* wo = (const float*)d_in[10];
  const float* bo = (const float*)d_in[11];

  // workspace layout (needs >= 76MB)
  u16* ws  = (u16*)d_ws;
  u16* wtq = ws;                       // 4 x 1M bf16 (W^T)
  u16* wtk = wtq + (1u << 20);
  u16* wtv = wtk + (1u << 20);
  u16* wto = wtv + (1u << 20);
  u16* Qb  = wto + (1u << 20);         // (B,H,S,dh) bf16
  u16* Kb  = Qb + (size_t)8192 * 1024; // (B,H,S,dh) bf16
  u16* Vtb = Kb + (size_t)8192 * 1024; // (B,H,dh,S) bf16
  u16* ctx = Vtb + (size_t)8192 * 1024;// (B,S,H*dh) bf16

  transpose_w<<<dim3(16, 16, 4), 256, 0, stream>>>(wq, wk, wv, wo, wtq);
  gemm_qkv<<<dim3(8, 64, 3), 256, 0, stream>>>(q_in, k_in, v_in, wtq, wtk, wtv,
                                               bq, bk, bv, Qb, Kb, Vtb);
  attn<<<dim3(32, 64), 256, 0, stream>>>(Qb, Kb, Vtb, mask, ctx);
  gemm_out<<<dim3(8, 64), 256, 0, stream>>>(ctx, wto, bo, (float*)d_out);
}

// Round 2
// 341.499 us; speedup vs baseline: 1.2350x; 1.2350x over previous
//
#include <hip/hip_runtime.h>
#include <stdint.h>

// MultiHeadAttention: B=4, S=2048, D_MODEL=1024, H=16, dh=64
// Pipeline:
//   1. transpose_w : w{q,k,v,o} fp32 (K x N) -> bf16 W^T (N x K) in ws
//   2. gemm_qkv    : X @ W + b -> Q (scaled 0.125*log2e), K, V^T bf16
//   3. attn        : flash attention, swapped QK^T (S^T in regs), in-register
//                    online softmax (exp2 domain), defer-max THR=8
//   4. gemm_out    : ctx @ wo^T + bo -> d_out fp32

typedef unsigned short u16;
typedef __attribute__((ext_vector_type(8))) short bf16x8;
typedef __attribute__((ext_vector_type(4))) float f32x4;

#define LOG2E 1.4426950408889634f

__device__ __forceinline__ u16 f2bf(float f) {
  uint32_t u = __builtin_bit_cast(uint32_t, f);
  u += 0x7fffu + ((u >> 16) & 1u);   // RNE
  return (u16)(u >> 16);
}
__device__ __forceinline__ uint32_t pack2(float a, float b) {
  return (uint32_t)f2bf(a) | ((uint32_t)f2bf(b) << 16);
}

// ---------------- weight transpose + bf16 convert ----------------
__global__ __launch_bounds__(256) void transpose_w(
    const float* __restrict__ W0, const float* __restrict__ W1,
    const float* __restrict__ W2, const float* __restrict__ W3,
    u16* __restrict__ Wt)
{
  const int z = blockIdx.z;
  const float* W = (z == 0) ? W0 : (z == 1) ? W1 : (z == 2) ? W2 : W3;
  u16* T = Wt + ((size_t)z << 20);
  const int n0 = blockIdx.x * 64, k0 = blockIdx.y * 64;
  const int tid = threadIdx.x;
  const int r = tid >> 4, c4 = (tid & 15) * 4;
  __shared__ float t[64][65];
#pragma unroll
  for (int j = 0; j < 4; ++j) {
    const int row = r + j * 16;
    const float4 v = *(const float4*)(W + (size_t)(k0 + row) * 1024 + n0 + c4);
    t[c4 + 0][row] = v.x; t[c4 + 1][row] = v.y;
    t[c4 + 2][row] = v.z; t[c4 + 3][row] = v.w;
  }
  __syncthreads();
#pragma unroll
  for (int j = 0; j < 4; ++j) {
    const int nrow = r + j * 16;
    ushort4 o;
    o.x = f2bf(t[nrow][c4 + 0]); o.y = f2bf(t[nrow][c4 + 1]);
    o.z = f2bf(t[nrow][c4 + 2]); o.w = f2bf(t[nrow][c4 + 3]);
    *(ushort4*)(T + (size_t)(n0 + nrow) * 1024 + k0 + c4) = o;
  }
}

// ---------------- QKV projection GEMM ----------------
__global__ __launch_bounds__(256) void gemm_qkv(
    const float* __restrict__ Xq, const float* __restrict__ Xk, const float* __restrict__ Xv,
    const u16* __restrict__ Wtq, const u16* __restrict__ Wtk, const u16* __restrict__ Wtv,
    const float* __restrict__ Bq, const float* __restrict__ Bk, const float* __restrict__ Bv,
    u16* __restrict__ Qo, u16* __restrict__ Ko, u16* __restrict__ Vto)
{
  const int z = blockIdx.z;
  const float* X = (z == 0) ? Xq : (z == 1) ? Xk : Xv;
  const u16* Wt  = (z == 0) ? Wtq : (z == 1) ? Wtk : Wtv;
  const float* Bi = (z == 0) ? Bq : (z == 1) ? Bk : Bv;

  const int m0 = blockIdx.y * 128;
  const int n0 = blockIdx.x * 128;
  const int tid = threadIdx.x;
  const int w = tid >> 6, l = tid & 63, lo = l & 15, hi = l >> 4;
  const int wr = w >> 1, wc = w & 1;

  __shared__ __align__(16) u16 As[128 * 56];
  __shared__ __align__(16) u16 Bs[128 * 56];

  const f32x4 fz = {0.f, 0.f, 0.f, 0.f};
  f32x4 acc[4][4];
#pragma unroll
  for (int m = 0; m < 4; ++m)
#pragma unroll
    for (int n = 0; n < 4; ++n) acc[m][n] = fz;

  const int srow = tid >> 1, shalf = (tid & 1) * 16;

  for (int k0 = 0; k0 < 1024; k0 += 32) {
    const float* ap = X + (size_t)(m0 + srow) * 1024 + k0 + shalf;
    const float4 a0 = *(const float4*)(ap);
    const float4 a1 = *(const float4*)(ap + 4);
    const float4 a2 = *(const float4*)(ap + 8);
    const float4 a3 = *(const float4*)(ap + 12);
    const u16* bp = Wt + (size_t)(n0 + srow) * 1024 + k0 + shalf;
    const uint4 b0 = *(const uint4*)(bp);
    const uint4 b1 = *(const uint4*)(bp + 8);

    __syncthreads();

    uint4 c0, c1;
    c0.x = pack2(a0.x, a0.y); c0.y = pack2(a0.z, a0.w);
    c0.z = pack2(a1.x, a1.y); c0.w = pack2(a1.z, a1.w);
    c1.x = pack2(a2.x, a2.y); c1.y = pack2(a2.z, a2.w);
    c1.z = pack2(a3.x, a3.y); c1.w = pack2(a3.z, a3.w);
    *(uint4*)&As[srow * 56 + shalf] = c0;
    *(uint4*)&As[srow * 56 + shalf + 8] = c1;
    *(uint4*)&Bs[srow * 56 + shalf] = b0;
    *(uint4*)&Bs[srow * 56 + shalf + 8] = b1;
    __syncthreads();

    bf16x8 af[4], bv_[4];
#pragma unroll
    for (int m = 0; m < 4; ++m)
      af[m] = *(const bf16x8*)&As[(wr * 64 + m * 16 + lo) * 56 + hi * 8];
#pragma unroll
    for (int n = 0; n < 4; ++n)
      bv_[n] = *(const bf16x8*)&Bs[(wc * 64 + n * 16 + lo) * 56 + hi * 8];
#pragma unroll
    for (int m = 0; m < 4; ++m)
#pragma unroll
      for (int n = 0; n < 4; ++n)
        acc[m][n] = __builtin_amdgcn_mfma_f32_16x16x32_bf16(af[m], bv_[n], acc[m][n], 0, 0, 0);
  }

#pragma unroll
  for (int m = 0; m < 4; ++m) {
#pragma unroll
    for (int n = 0; n < 4; ++n) {
      const int col = n0 + wc * 64 + n * 16 + lo;   // n = h*64 + d
      const float bc = Bi[col];
      const int h = col >> 6, d = col & 63;
#pragma unroll
      for (int i = 0; i < 4; ++i) {
        const int r = m0 + wr * 64 + m * 16 + hi * 4 + i;  // r = b*2048 + s
        const int b = r >> 11, s = r & 2047;
        float v = acc[m][n][i] + bc;
        if (z == 0) {
          v *= 0.125f * LOG2E;  // fold 1/sqrt(dh) and log2(e) (exp2-domain softmax)
          Qo[((size_t)((b * 16 + h) * 2048 + s)) * 64 + d] = f2bf(v);
        } else if (z == 1) {
          Ko[((size_t)((b * 16 + h) * 2048 + s)) * 64 + d] = f2bf(v);
        } else {
          Vto[((size_t)((b * 16 + h) * 64 + d)) * 2048 + s] = f2bf(v);
        }
      }
    }
  }
}

// ---------------- flash attention (swapped QK^T, in-register softmax) ----
// grid (32 q-tiles, 64 b*h), 4 waves, 16 q rows per wave, KBLK=64.
// S^T = mfma(K_frag, Q_frag): lane holds S^T[kv=16f+4hi+i][q=lo] -> row stats
// are per-lane scalars (reduce: 15 in-reg ops + shfl_xor 16/32).
// P exchange: per-wave LDS u32 [t=kv/2][20-stride][q] -> <=2-way banks.
__global__ __launch_bounds__(256) void attn(
    const u16* __restrict__ Q, const u16* __restrict__ K,
    const u16* __restrict__ Vt, const float* __restrict__ mask,
    u16* __restrict__ Ctx)
{
  const int qt = blockIdx.x;
  const int bh = blockIdx.y;
  const int b = bh >> 4, h = bh & 15;
  const int tid = threadIdx.x;
  const int w = tid >> 6, l = tid & 63, lo = l & 15, hi = l >> 4;

  __shared__ __align__(16) u16 Kl[64 * 72];
  __shared__ __align__(16) u16 Vl[64 * 72];
  __shared__ __align__(16) uint32_t Plw[4][32 * 20];

  const u16* Qb = Q + (size_t)bh * (2048 * 64);
  const u16* Kb = K + (size_t)bh * (2048 * 64);
  const u16* Vb = Vt + (size_t)bh * (64 * 2048);
  const float* mb = mask + (size_t)b * 2048;

  const int qrow = qt * 64 + w * 16 + lo;
  const bf16x8 qa0 = *(const bf16x8*)(Qb + (size_t)qrow * 64 + hi * 8);
  const bf16x8 qa1 = *(const bf16x8*)(Qb + (size_t)qrow * 64 + 32 + hi * 8);

  const f32x4 fz = {0.f, 0.f, 0.f, 0.f};
  f32x4 o[4] = {fz, fz, fz, fz};
  float mrun = -1e30f, lrun = 0.f;   // stats for q = lo (replicated over hi)

  uint32_t* Pw = &Plw[w][0];
  const int srow = tid >> 2;
  const int sq = (tid & 3) * 16;
  const float MS = -1.0e9f * LOG2E;

  for (int kt = 0; kt < 32; ++kt) {
    const int kv0 = kt * 64;
    // global loads issued before barrier (overlap w/ prev compute)
    const u16* kp = Kb + (size_t)(kv0 + srow) * 64 + sq;
    const uint4 k0v = *(const uint4*)kp;
    const uint4 k1v = *(const uint4*)(kp + 8);
    const u16* vp = Vb + (size_t)srow * 2048 + kv0 + sq;
    const uint4 v0v = *(const uint4*)vp;
    const uint4 v1v = *(const uint4*)(vp + 8);
    float4 m4[4];
#pragma unroll
    for (int f = 0; f < 4; ++f)
      m4[f] = *(const float4*)(mb + kv0 + 16 * f + 4 * hi);

    __syncthreads();
    *(uint4*)&Kl[srow * 72 + sq] = k0v;
    *(uint4*)&Kl[srow * 72 + sq + 8] = k1v;
    *(uint4*)&Vl[srow * 72 + sq] = v0v;
    *(uint4*)&Vl[srow * 72 + sq + 8] = v1v;
    __syncthreads();

    // S^T[kv][q]: kv = 16f + 4hi + i, q = lo  (already log2-domain)
    f32x4 st[4];
#pragma unroll
    for (int f = 0; f < 4; ++f) {
      const int krow = (f * 16 + lo) * 72;
      const bf16x8 kb0 = *(const bf16x8*)&Kl[krow + hi * 8];
      const bf16x8 kb1 = *(const bf16x8*)&Kl[krow + 32 + hi * 8];
      f32x4 a = __builtin_amdgcn_mfma_f32_16x16x32_bf16(kb0, qa0, fz, 0, 0, 0);
      st[f] = __builtin_amdgcn_mfma_f32_16x16x32_bf16(kb1, qa1, a, 0, 0, 0);
    }
    // add mask, reduce max over the 64-kv block for row q=lo
    float mx = -1e30f;
#pragma unroll
    for (int f = 0; f < 4; ++f) {
      st[f][0] += m4[f].x * MS; st[f][1] += m4[f].y * MS;
      st[f][2] += m4[f].z * MS; st[f][3] += m4[f].w * MS;
      mx = fmaxf(mx, fmaxf(fmaxf(st[f][0], st[f][1]), fmaxf(st[f][2], st[f][3])));
    }
    mx = fmaxf(mx, __shfl_xor(mx, 16));
    mx = fmaxf(mx, __shfl_xor(mx, 32));

    // defer-max: only rescale when max grew by > 8 (exp2 domain, bound 256)
    if (!__all(mx - mrun <= 8.0f)) {
      const float mn = fmaxf(mrun, mx);
      const float sc = exp2f(mrun - mn);
      mrun = mn;
      lrun *= sc;
      float scq[4];
#pragma unroll
      for (int i = 0; i < 4; ++i) scq[i] = __shfl(sc, hi * 4 + i);
#pragma unroll
      for (int nf = 0; nf < 4; ++nf) {
        o[nf][0] *= scq[0]; o[nf][1] *= scq[1];
        o[nf][2] *= scq[2]; o[nf][3] *= scq[3];
      }
    }

    // P = exp2(S - m), pack to bf16 pairs, per-lane row-sum
    float rs = 0.f;
#pragma unroll
    for (int f = 0; f < 4; ++f) {
      const float p0 = exp2f(st[f][0] - mrun);
      const float p1 = exp2f(st[f][1] - mrun);
      const float p2 = exp2f(st[f][2] - mrun);
      const float p3 = exp2f(st[f][3] - mrun);
      rs += (p0 + p1) + (p2 + p3);
      const int t = 8 * f + 2 * hi;           // kv-pair index
      Pw[t * 20 + lo] = pack2(p0, p1);
      Pw[(t + 1) * 20 + lo] = pack2(p2, p3);
    }
    rs += __shfl_xor(rs, 16);
    rs += __shfl_xor(rs, 32);
    lrun += rs;

    __builtin_amdgcn_wave_barrier();  // keep P writes before P reads

    // gather P A-frags: lane needs P[q=lo][kv = kk*32 + 8hi + j]
    union { uint32_t u[4]; bf16x8 v; } pa0, pa1;
#pragma unroll
    for (int u = 0; u < 4; ++u) {
      pa0.u[u] = Pw[(4 * hi + u) * 20 + lo];
      pa1.u[u] = Pw[(16 + 4 * hi + u) * 20 + lo];
    }

    // PV: O[q][d] += P(16x64) @ V(64x64)
#pragma unroll
    for (int nf = 0; nf < 4; ++nf) {
      const int vrow = (nf * 16 + lo) * 72;
      const bf16x8 vb0 = *(const bf16x8*)&Vl[vrow + hi * 8];
      const bf16x8 vb1 = *(const bf16x8*)&Vl[vrow + 32 + hi * 8];
      o[nf] = __builtin_amdgcn_mfma_f32_16x16x32_bf16(pa0.v, vb0, o[nf], 0, 0, 0);
      o[nf] = __builtin_amdgcn_mfma_f32_16x16x32_bf16(pa1.v, vb1, o[nf], 0, 0, 0);
    }
  }

  const float linv = 1.f / lrun;
  float invq[4];
#pragma unroll
  for (int i = 0; i < 4; ++i) invq[i] = __shfl(linv, hi * 4 + i);
#pragma unroll
  for (int nf = 0; nf < 4; ++nf) {
#pragma unroll
    for (int i = 0; i < 4; ++i) {
      const int s = qt * 64 + w * 16 + hi * 4 + i;
      const int d = nf * 16 + lo;
      Ctx[((size_t)((b * 2048 + s) * 16 + h)) * 64 + d] = f2bf(o[nf][i] * invq[i]);
    }
  }
}

// ---------------- output projection GEMM ----------------
__global__ __launch_bounds__(256) void gemm_out(
    const u16* __restrict__ Ctx, const u16* __restrict__ Wt,
    const float* __restrict__ Bo, float* __restrict__ Out)
{
  const int m0 = blockIdx.y * 128;
  const int n0 = blockIdx.x * 128;
  const int tid = threadIdx.x;
  const int w = tid >> 6, l = tid & 63, lo = l & 15, hi = l >> 4;
  const int wr = w >> 1, wc = w & 1;

  __shared__ __align__(16) u16 As[128 * 56];
  __shared__ __align__(16) u16 Bs[128 * 56];

  const f32x4 fz = {0.f, 0.f, 0.f, 0.f};
  f32x4 acc[4][4];
#pragma unroll
  for (int m = 0; m < 4; ++m)
#pragma unroll
    for (int n = 0; n < 4; ++n) acc[m][n] = fz;

  const int srow = tid >> 1, shalf = (tid & 1) * 16;

  for (int k0 = 0; k0 < 1024; k0 += 32) {
    const u16* ap = Ctx + (size_t)(m0 + srow) * 1024 + k0 + shalf;
    const uint4 a0 = *(const uint4*)(ap);
    const uint4 a1 = *(const uint4*)(ap + 8);
    const u16* bp = Wt + (size_t)(n0 + srow) * 1024 + k0 + shalf;
    const uint4 b0 = *(const uint4*)(bp);
    const uint4 b1 = *(const uint4*)(bp + 8);

    __syncthreads();
    *(uint4*)&As[srow * 56 + shalf] = a0;
    *(uint4*)&As[srow * 56 + shalf + 8] = a1;
    *(uint4*)&Bs[srow * 56 + shalf] = b0;
    *(uint4*)&Bs[srow * 56 + shalf + 8] = b1;
    __syncthreads();

    bf16x8 af[4], bv_[4];
#pragma unroll
    for (int m = 0; m < 4; ++m)
      af[m] = *(const bf16x8*)&As[(wr * 64 + m * 16 + lo) * 56 + hi * 8];
#pragma unroll
    for (int n = 0; n < 4; ++n)
      bv_[n] = *(const bf16x8*)&Bs[(wc * 64 + n * 16 + lo) * 56 + hi * 8];
#pragma unroll
    for (int m = 0; m < 4; ++m)
#pragma unroll
      for (int n = 0; n < 4; ++n)
        acc[m][n] = __builtin_amdgcn_mfma_f32_16x16x32_bf16(af[m], bv_[n], acc[m][n], 0, 0, 0);
  }

#pragma unroll
  for (int m = 0; m < 4; ++m) {
#pragma unroll
    for (int n = 0; n < 4; ++n) {
      const int col = n0 + wc * 64 + n * 16 + lo;
      const float bc = Bo[col];
#pragma unroll
      for (int i = 0; i < 4; ++i) {
        const int r = m0 + wr * 64 + m * 16 + hi * 4 + i;
        Out[(size_t)r * 1024 + col] = acc[m][n][i] + bc;
      }
    }
  }
}

extern "C" void kernel_launch(void* const* d_in, const int* in_sizes, int n_in,
                              void* d_out, int out_size, void* d_ws, size_t ws_size,
                              hipStream_t stream) {
  const float* q_in = (const float*)d_in[0];
  const float* k_in = (const float*)d_in[1];
  const float* v_in = (const float*)d_in[2];
  const float* mask = (const float*)d_in[3];
  const float* wq = (const float*)d_in[4];
  const float* bq = (const float*)d_in[5];
  const float* wk = (const float*)d_in[6];
  const float* bk = (const float*)d_in[7];
  const float* wv = (const float*)d_in[8];
  const float* bv = (const float*)d_in[9];
  const float* wo = (const float*)d_in[10];
  const float* bo = (const float*)d_in[11];

  u16* ws  = (u16*)d_ws;
  u16* wtq = ws;
  u16* wtk = wtq + (1u << 20);
  u16* wtv = wtk + (1u << 20);
  u16* wto = wtv + (1u << 20);
  u16* Qb  = wto + (1u << 20);
  u16* Kb  = Qb + (size_t)8192 * 1024;
  u16* Vtb = Kb + (size_t)8192 * 1024;
  u16* ctx = Vtb + (size_t)8192 * 1024;

  transpose_w<<<dim3(16, 16, 4), 256, 0, stream>>>(wq, wk, wv, wo, wtq);
  gemm_qkv<<<dim3(8, 64, 3), 256, 0, stream>>>(q_in, k_in, v_in, wtq, wtk, wtv,
                                               bq, bk, bv, Qb, Kb, Vtb);
  attn<<<dim3(32, 64), 256, 0, stream>>>(Qb, Kb, Vtb, mask, ctx);
  gemm_out<<<dim3(8, 64), 256, 0, stream>>>(ctx, wto, bo, (float*)d_out);
}

// Round 3
// 302.261 us; speedup vs baseline: 1.3953x; 1.1298x over previous
//
#include <hip/hip_runtime.h>
#include <stdint.h>

// MultiHeadAttention: B=4, S=2048, D_MODEL=1024, H=16, dh=64
// R3: v_cvt_pk_bf16_f32 packing (T12 primitive), XOR-swizzled K/V LDS tiles
//     (T2/G4), XCD-chunked block swizzle (T1), s_setprio around attn MFMA (T5).

typedef unsigned short u16;
typedef __attribute__((ext_vector_type(8))) short bf16x8;
typedef __attribute__((ext_vector_type(4))) float f32x4;

#define LOG2E 1.4426950408889634f

__device__ __forceinline__ u16 f2bf(float f) {
  uint32_t u = __builtin_bit_cast(uint32_t, f);
  u += 0x7fffu + ((u >> 16) & 1u);   // RNE
  return (u16)(u >> 16);
}
// packed f32x2 -> bf16x2 (RNE), single VALU op; no builtin on gfx950 (m240)
__device__ __forceinline__ uint32_t cvt_pk(float a, float b) {
  uint32_t r;
  asm("v_cvt_pk_bf16_f32 %0, %1, %2" : "=v"(r) : "v"(a), "v"(b));
  return r;
}

// ---------------- weight transpose + bf16 convert ----------------
__global__ __launch_bounds__(256) void transpose_w(
    const float* __restrict__ W0, const float* __restrict__ W1,
    const float* __restrict__ W2, const float* __restrict__ W3,
    u16* __restrict__ Wt)
{
  const int z = blockIdx.z;
  const float* W = (z == 0) ? W0 : (z == 1) ? W1 : (z == 2) ? W2 : W3;
  u16* T = Wt + ((size_t)z << 20);
  const int n0 = blockIdx.x * 64, k0 = blockIdx.y * 64;
  const int tid = threadIdx.x;
  const int r = tid >> 4, c4 = (tid & 15) * 4;
  __shared__ float t[64][65];
#pragma unroll
  for (int j = 0; j < 4; ++j) {
    const int row = r + j * 16;
    const float4 v = *(const float4*)(W + (size_t)(k0 + row) * 1024 + n0 + c4);
    t[c4 + 0][row] = v.x; t[c4 + 1][row] = v.y;
    t[c4 + 2][row] = v.z; t[c4 + 3][row] = v.w;
  }
  __syncthreads();
#pragma unroll
  for (int j = 0; j < 4; ++j) {
    const int nrow = r + j * 16;
    uint32_t o0 = cvt_pk(t[nrow][c4 + 0], t[nrow][c4 + 1]);
    uint32_t o1 = cvt_pk(t[nrow][c4 + 2], t[nrow][c4 + 3]);
    uint2 o = {o0, o1};
    *(uint2*)(T + (size_t)(n0 + nrow) * 1024 + k0 + c4) = o;
  }
}

// ---------------- QKV projection GEMM ----------------
// 1-D grid 1536, XCD-chunked: nid=(bid%8)*192+bid/8; z=nid>>9; x=nid&7; y=(nid&511)>>3.
__global__ __launch_bounds__(256) void gemm_qkv(
    const float* __restrict__ Xq, const float* __restrict__ Xk, const float* __restrict__ Xv,
    const u16* __restrict__ Wtq, const u16* __restrict__ Wtk, const u16* __restrict__ Wtv,
    const float* __restrict__ Bq, const float* __restrict__ Bk, const float* __restrict__ Bv,
    u16* __restrict__ Qo, u16* __restrict__ Ko, u16* __restrict__ Vto)
{
  const int bid = blockIdx.x;
  const int nid = (bid & 7) * 192 + (bid >> 3);
  const int z = nid >> 9;
  const int rem = nid & 511;
  const int n0 = (rem & 7) * 128;
  const int m0 = (rem >> 3) * 128;

  const float* X = (z == 0) ? Xq : (z == 1) ? Xk : Xv;
  const u16* Wt  = (z == 0) ? Wtq : (z == 1) ? Wtk : Wtv;
  const float* Bi = (z == 0) ? Bq : (z == 1) ? Bk : Bv;

  const int tid = threadIdx.x;
  const int w = tid >> 6, l = tid & 63, lo = l & 15, hi = l >> 4;
  const int wr = w >> 1, wc = w & 1;

  __shared__ __align__(16) u16 As[128 * 56];
  __shared__ __align__(16) u16 Bs[128 * 56];

  const f32x4 fz = {0.f, 0.f, 0.f, 0.f};
  f32x4 acc[4][4];
#pragma unroll
  for (int m = 0; m < 4; ++m)
#pragma unroll
    for (int n = 0; n < 4; ++n) acc[m][n] = fz;

  const int srow = tid >> 1, shalf = (tid & 1) * 16;

  for (int k0 = 0; k0 < 1024; k0 += 32) {
    const float* ap = X + (size_t)(m0 + srow) * 1024 + k0 + shalf;
    const float4 a0 = *(const float4*)(ap);
    const float4 a1 = *(const float4*)(ap + 4);
    const float4 a2 = *(const float4*)(ap + 8);
    const float4 a3 = *(const float4*)(ap + 12);
    const u16* bp = Wt + (size_t)(n0 + srow) * 1024 + k0 + shalf;
    const uint4 b0 = *(const uint4*)(bp);
    const uint4 b1 = *(const uint4*)(bp + 8);

    __syncthreads();

    uint4 c0, c1;
    c0.x = cvt_pk(a0.x, a0.y); c0.y = cvt_pk(a0.z, a0.w);
    c0.z = cvt_pk(a1.x, a1.y); c0.w = cvt_pk(a1.z, a1.w);
    c1.x = cvt_pk(a2.x, a2.y); c1.y = cvt_pk(a2.z, a2.w);
    c1.z = cvt_pk(a3.x, a3.y); c1.w = cvt_pk(a3.z, a3.w);
    *(uint4*)&As[srow * 56 + shalf] = c0;
    *(uint4*)&As[srow * 56 + shalf + 8] = c1;
    *(uint4*)&Bs[srow * 56 + shalf] = b0;
    *(uint4*)&Bs[srow * 56 + shalf + 8] = b1;
    __syncthreads();

    bf16x8 af[4], bv_[4];
#pragma unroll
    for (int m = 0; m < 4; ++m)
      af[m] = *(const bf16x8*)&As[(wr * 64 + m * 16 + lo) * 56 + hi * 8];
#pragma unroll
    for (int n = 0; n < 4; ++n)
      bv_[n] = *(const bf16x8*)&Bs[(wc * 64 + n * 16 + lo) * 56 + hi * 8];
#pragma unroll
    for (int m = 0; m < 4; ++m)
#pragma unroll
      for (int n = 0; n < 4; ++n)
        acc[m][n] = __builtin_amdgcn_mfma_f32_16x16x32_bf16(af[m], bv_[n], acc[m][n], 0, 0, 0);
  }

#pragma unroll
  for (int m = 0; m < 4; ++m) {
#pragma unroll
    for (int n = 0; n < 4; ++n) {
      const int col = n0 + wc * 64 + n * 16 + lo;   // col = h*64 + d
      const float bc = Bi[col];
      const int h = col >> 6, d = col & 63;
#pragma unroll
      for (int i = 0; i < 4; ++i) {
        const int r = m0 + wr * 64 + m * 16 + hi * 4 + i;  // r = b*2048 + s
        const int b = r >> 11, s = r & 2047;
        float v = acc[m][n][i] + bc;
        if (z == 0) {
          v *= 0.125f * LOG2E;  // fold 1/sqrt(dh) and log2(e)
          Qo[((size_t)((b * 16 + h) * 2048 + s)) * 64 + d] = f2bf(v);
        } else if (z == 1) {
          Ko[((size_t)((b * 16 + h) * 2048 + s)) * 64 + d] = f2bf(v);
        } else {
          Vto[((size_t)((b * 16 + h) * 64 + d)) * 2048 + s] = f2bf(v);
        }
      }
    }
  }
}

// ---------------- flash attention ----------------
// 1-D grid 2048, XCD-chunked (32 qt-blocks sharing a (b,h) K/V panel land on
// one XCD). K/V tiles: linear [64][64] u16 with 16B-slot XOR swizzle
// slot_phys = slot ^ (row&7)  (T2/G4) on both write and read sides.
__global__ __launch_bounds__(256) void attn(
    const u16* __restrict__ Q, const u16* __restrict__ K,
    const u16* __restrict__ Vt, const float* __restrict__ mask,
    u16* __restrict__ Ctx)
{
  const int bid = blockIdx.x;
  const int nid = (bid & 7) * 256 + (bid >> 3);
  const int qt = nid & 31;
  const int bh = nid >> 5;
  const int b = bh >> 4, h = bh & 15;
  const int tid = threadIdx.x;
  const int w = tid >> 6, l = tid & 63, lo = l & 15, hi = l >> 4;

  __shared__ __align__(16) u16 Kl[64 * 64];
  __shared__ __align__(16) u16 Vl[64 * 64];
  __shared__ __align__(16) uint32_t Plw[4][32 * 20];

  const u16* Qb = Q + (size_t)bh * (2048 * 64);
  const u16* Kb = K + (size_t)bh * (2048 * 64);
  const u16* Vb = Vt + (size_t)bh * (64 * 2048);
  const float* mb = mask + (size_t)b * 2048;

  const int qrow = qt * 64 + w * 16 + lo;
  const bf16x8 qa0 = *(const bf16x8*)(Qb + (size_t)qrow * 64 + hi * 8);
  const bf16x8 qa1 = *(const bf16x8*)(Qb + (size_t)qrow * 64 + 32 + hi * 8);

  const f32x4 fz = {0.f, 0.f, 0.f, 0.f};
  f32x4 o[4] = {fz, fz, fz, fz};
  float mrun = -1e30f, lrun = 0.f;   // stats for q = lo (replicated over hi)

  uint32_t* Pw = &Plw[w][0];
  const int srow = tid >> 2;          // staging row 0..63
  const int q4 = tid & 3;
  const int s7 = srow & 7;
  // swizzled write offsets (constant per thread)
  u16* kw0 = &Kl[srow * 64 + (((2 * q4)     ^ s7) << 3)];
  u16* kw1 = &Kl[srow * 64 + (((2 * q4 + 1) ^ s7) << 3)];
  u16* vw0 = &Vl[srow * 64 + (((2 * q4)     ^ s7) << 3)];
  u16* vw1 = &Vl[srow * 64 + (((2 * q4 + 1) ^ s7) << 3)];
  const int lo7 = lo & 7;
  const float MS = -1.0e9f * LOG2E;

  for (int kt = 0; kt < 32; ++kt) {
    const int kv0 = kt * 64;
    // global loads issued before barrier (overlap w/ prev compute)
    const u16* kp = Kb + (size_t)(kv0 + srow) * 64 + q4 * 16;
    const uint4 k0v = *(const uint4*)kp;
    const uint4 k1v = *(const uint4*)(kp + 8);
    const u16* vp = Vb + (size_t)srow * 2048 + kv0 + q4 * 16;
    const uint4 v0v = *(const uint4*)vp;
    const uint4 v1v = *(const uint4*)(vp + 8);
    float4 m4[4];
#pragma unroll
    for (int f = 0; f < 4; ++f)
      m4[f] = *(const float4*)(mb + kv0 + 16 * f + 4 * hi);

    __syncthreads();
    *(uint4*)kw0 = k0v;
    *(uint4*)kw1 = k1v;
    *(uint4*)vw0 = v0v;
    *(uint4*)vw1 = v1v;
    __syncthreads();

    // S^T[kv][q]: kv = 16f + 4hi + i, q = lo (log2-domain; scale folded in Q)
    f32x4 st[4];
    __builtin_amdgcn_s_setprio(1);
#pragma unroll
    for (int f = 0; f < 4; ++f) {
      const int krow = (f * 16 + lo) * 64;
      const bf16x8 kb0 = *(const bf16x8*)&Kl[krow + ((hi ^ lo7) << 3)];
      const bf16x8 kb1 = *(const bf16x8*)&Kl[krow + (((4 + hi) ^ lo7) << 3)];
      f32x4 a = __builtin_amdgcn_mfma_f32_16x16x32_bf16(kb0, qa0, fz, 0, 0, 0);
      st[f] = __builtin_amdgcn_mfma_f32_16x16x32_bf16(kb1, qa1, a, 0, 0, 0);
    }
    __builtin_amdgcn_s_setprio(0);

    // add mask, block-max for row q=lo
    float mx = -1e30f;
#pragma unroll
    for (int f = 0; f < 4; ++f) {
      st[f][0] += m4[f].x * MS; st[f][1] += m4[f].y * MS;
      st[f][2] += m4[f].z * MS; st[f][3] += m4[f].w * MS;
      mx = fmaxf(mx, fmaxf(fmaxf(st[f][0], st[f][1]), fmaxf(st[f][2], st[f][3])));
    }
    mx = fmaxf(mx, __shfl_xor(mx, 16));
    mx = fmaxf(mx, __shfl_xor(mx, 32));

    // defer-max: only rescale when max grew by > 8 (exp2 domain, bound 256)
    if (!__all(mx - mrun <= 8.0f)) {
      const float mn = fmaxf(mrun, mx);
      const float sc = exp2f(mrun - mn);
      mrun = mn;
      lrun *= sc;
      float scq[4];
#pragma unroll
      for (int i = 0; i < 4; ++i) scq[i] = __shfl(sc, hi * 4 + i);
#pragma unroll
      for (int nf = 0; nf < 4; ++nf) {
        o[nf][0] *= scq[0]; o[nf][1] *= scq[1];
        o[nf][2] *= scq[2]; o[nf][3] *= scq[3];
      }
    }

    // P = exp2(S - m), cvt_pk to bf16 pairs, per-lane row-sum
    float rs = 0.f;
#pragma unroll
    for (int f = 0; f < 4; ++f) {
      const float p0 = exp2f(st[f][0] - mrun);
      const float p1 = exp2f(st[f][1] - mrun);
      const float p2 = exp2f(st[f][2] - mrun);
      const float p3 = exp2f(st[f][3] - mrun);
      rs += (p0 + p1) + (p2 + p3);
      const int t = 8 * f + 2 * hi;           // kv-pair index
      Pw[t * 20 + lo] = cvt_pk(p0, p1);
      Pw[(t + 1) * 20 + lo] = cvt_pk(p2, p3);
    }
    rs += __shfl_xor(rs, 16);
    rs += __shfl_xor(rs, 32);
    lrun += rs;

    __builtin_amdgcn_wave_barrier();  // keep P writes before P reads

    // gather P A-frags: lane needs P[q=lo][kv = kk*32 + 8hi + j]
    union { uint32_t u[4]; bf16x8 v; } pa0, pa1;
#pragma unroll
    for (int u = 0; u < 4; ++u) {
      pa0.u[u] = Pw[(4 * hi + u) * 20 + lo];
      pa1.u[u] = Pw[(16 + 4 * hi + u) * 20 + lo];
    }

    // PV: O[q][d] += P(16x64) @ V(64x64)
    __builtin_amdgcn_s_setprio(1);
#pragma unroll
    for (int nf = 0; nf < 4; ++nf) {
      const int vrow = (nf * 16 + lo) * 64;
      const bf16x8 vb0 = *(const bf16x8*)&Vl[vrow + ((hi ^ lo7) << 3)];
      const bf16x8 vb1 = *(const bf16x8*)&Vl[vrow + (((4 + hi) ^ lo7) << 3)];
      o[nf] = __builtin_amdgcn_mfma_f32_16x16x32_bf16(pa0.v, vb0, o[nf], 0, 0, 0);
      o[nf] = __builtin_amdgcn_mfma_f32_16x16x32_bf16(pa1.v, vb1, o[nf], 0, 0, 0);
    }
    __builtin_amdgcn_s_setprio(0);
  }

  const float linv = 1.f / lrun;
  float invq[4];
#pragma unroll
  for (int i = 0; i < 4; ++i) invq[i] = __shfl(linv, hi * 4 + i);
#pragma unroll
  for (int nf = 0; nf < 4; ++nf) {
#pragma unroll
    for (int i = 0; i < 4; ++i) {
      const int s = qt * 64 + w * 16 + hi * 4 + i;
      const int d = nf * 16 + lo;
      Ctx[((size_t)((b * 2048 + s) * 16 + h)) * 64 + d] = f2bf(o[nf][i] * invq[i]);
    }
  }
}

// ---------------- output projection GEMM ----------------
// 1-D grid 512, XCD-chunked: nid=(bid%8)*64+bid/8; x=nid&7; y=nid>>3.
__global__ __launch_bounds__(256) void gemm_out(
    const u16* __restrict__ Ctx, const u16* __restrict__ Wt,
    const float* __restrict__ Bo, float* __restrict__ Out)
{
  const int bid = blockIdx.x;
  const int nid = (bid & 7) * 64 + (bid >> 3);
  const int n0 = (nid & 7) * 128;
  const int m0 = (nid >> 3) * 128;
  const int tid = threadIdx.x;
  const int w = tid >> 6, l = tid & 63, lo = l & 15, hi = l >> 4;
  const int wr = w >> 1, wc = w & 1;

  __shared__ __align__(16) u16 As[128 * 56];
  __shared__ __align__(16) u16 Bs[128 * 56];

  const f32x4 fz = {0.f, 0.f, 0.f, 0.f};
  f32x4 acc[4][4];
#pragma unroll
  for (int m = 0; m < 4; ++m)
#pragma unroll
    for (int n = 0; n < 4; ++n) acc[m][n] = fz;

  const int srow = tid >> 1, shalf = (tid & 1) * 16;

  for (int k0 = 0; k0 < 1024; k0 += 32) {
    const u16* ap = Ctx + (size_t)(m0 + srow) * 1024 + k0 + shalf;
    const uint4 a0 = *(const uint4*)(ap);
    const uint4 a1 = *(const uint4*)(ap + 8);
    const u16* bp = Wt + (size_t)(n0 + srow) * 1024 + k0 + shalf;
    const uint4 b0 = *(const uint4*)(bp);
    const uint4 b1 = *(const uint4*)(bp + 8);

    __syncthreads();
    *(uint4*)&As[srow * 56 + shalf] = a0;
    *(uint4*)&As[srow * 56 + shalf + 8] = a1;
    *(uint4*)&Bs[srow * 56 + shalf] = b0;
    *(uint4*)&Bs[srow * 56 + shalf + 8] = b1;
    __syncthreads();

    bf16x8 af[4], bv_[4];
#pragma unroll
    for (int m = 0; m < 4; ++m)
      af[m] = *(const bf16x8*)&As[(wr * 64 + m * 16 + lo) * 56 + hi * 8];
#pragma unroll
    for (int n = 0; n < 4; ++n)
      bv_[n] = *(const bf16x8*)&Bs[(wc * 64 + n * 16 + lo) * 56 + hi * 8];
#pragma unroll
    for (int m = 0; m < 4; ++m)
#pragma unroll
      for (int n = 0; n < 4; ++n)
        acc[m][n] = __builtin_amdgcn_mfma_f32_16x16x32_bf16(af[m], bv_[n], acc[m][n], 0, 0, 0);
  }

#pragma unroll
  for (int m = 0; m < 4; ++m) {
#pragma unroll
    for (int n = 0; n < 4; ++n) {
      const int col = n0 + wc * 64 + n * 16 + lo;
      const float bc = Bo[col];
#pragma unroll
      for (int i = 0; i < 4; ++i) {
        const int r = m0 + wr * 64 + m * 16 + hi * 4 + i;
        Out[(size_t)r * 1024 + col] = acc[m][n][i] + bc;
      }
    }
  }
}

extern "C" void kernel_launch(void* const* d_in, const int* in_sizes, int n_in,
                              void* d_out, int out_size, void* d_ws, size_t ws_size,
                              hipStream_t stream) {
  const float* q_in = (const float*)d_in[0];
  const float* k_in = (const float*)d_in[1];
  const float* v_in = (const float*)d_in[2];
  const float* mask = (const float*)d_in[3];
  const float* wq = (const float*)d_in[4];
  const float* bq = (const float*)d_in[5];
  const float* wk = (const float*)d_in[6];
  const float* bk = (const float*)d_in[7];
  const float* wv = (const float*)d_in[8];
  const float* bv = (const float*)d_in[9];
  const float* wo = (const float*)d_in[10];
  const float* bo = (const float*)d_in[11];

  u16* ws  = (u16*)d_ws;
  u16* wtq = ws;
  u16* wtk = wtq + (1u << 20);
  u16* wtv = wtk + (1u << 20);
  u16* wto = wtv + (1u << 20);
  u16* Qb  = wto + (1u << 20);
  u16* Kb  = Qb + (size_t)8192 * 1024;
  u16* Vtb = Kb + (size_t)8192 * 1024;
  u16* ctx = Vtb + (size_t)8192 * 1024;

  transpose_w<<<dim3(16, 16, 4), 256, 0, stream>>>(wq, wk, wv, wo, wtq);
  gemm_qkv<<<1536, 256, 0, stream>>>(q_in, k_in, v_in, wtq, wtk, wtv,
                                     bq, bk, bv, Qb, Kb, Vtb);
  attn<<<2048, 256, 0, stream>>>(Qb, Kb, Vtb, mask, ctx);
  gemm_out<<<512, 256, 0, stream>>>(ctx, wto, bo, (float*)d_out);
}